// Round 1
// baseline (232.620 us; speedup 1.0000x reference)
//
#include <hip/hip_runtime.h>
#include <math.h>

// Problem constants (static shapes from reference):
// x, x_r: (1, 3, 32, 512, 512) fp32. size=64 -> hc=wc=32, nh=nw=16.
// P[t,ph,pw] = mean over (c=3, 32x32) of |x - x_r|/2   (3072 elems / patch)
// out = log( mean_t( max(0, max_{ph,pw} P) ) )   -- scalar fp32.

#define CC 3
#define TT 32
#define HH 512
#define WW 512
#define NPATCH 8192   // 32 t * 16 * 16

__global__ __launch_bounds__(256) void patch_sum_kernel(
    const float* __restrict__ x, const float* __restrict__ xr,
    float* __restrict__ patch) {
  const int pidx = blockIdx.x;            // 0..8191 = t*256 + ph*16 + pw
  const int t  = pidx >> 8;
  const int ph = (pidx >> 4) & 15;
  const int pw = pidx & 15;
  const int tid = threadIdx.x;
  const int row = tid >> 3;               // 0..31 (patch row)
  const int col = (tid & 7) << 2;         // 0,4,...,28 (float4 col within patch)

  float acc = 0.f;
#pragma unroll
  for (int ch = 0; ch < CC; ++ch) {
    size_t off = ((size_t)(ch * TT + t) * HH + (size_t)(ph * 32 + row)) * WW
               + (size_t)(pw * 32 + col);
    float4 a = *(const float4*)(x + off);
    float4 b = *(const float4*)(xr + off);
    acc += fabsf(a.x - b.x) + fabsf(a.y - b.y)
         + fabsf(a.z - b.z) + fabsf(a.w - b.w);
  }

  // wave (64-lane) reduce, then cross-wave via LDS
#pragma unroll
  for (int o = 32; o > 0; o >>= 1) acc += __shfl_down(acc, o, 64);
  __shared__ float s[4];
  if ((tid & 63) == 0) s[tid >> 6] = acc;
  __syncthreads();
  if (tid == 0) {
    float tot = s[0] + s[1] + s[2] + s[3];
    // L = |x - x_r| * 0.5 ; patch mean over 3*32*32 = 3072 elements
    patch[pidx] = tot * (0.5f / 3072.0f);
  }
}

__global__ __launch_bounds__(256) void finalize_kernel(
    const float* __restrict__ patch, float* __restrict__ out) {
  const int tid = threadIdx.x;
  __shared__ float s[4];
  float total = 0.f;  // only meaningful on tid 0
  for (int t = 0; t < TT; ++t) {
    float v = patch[t * 256 + tid];
#pragma unroll
    for (int o = 32; o > 0; o >>= 1) v = fmaxf(v, __shfl_down(v, o, 64));
    if ((tid & 63) == 0) s[tid >> 6] = v;
    __syncthreads();
    if (tid == 0) {
      float m = fmaxf(fmaxf(s[0], s[1]), fmaxf(s[2], s[3]));
      total += fmaxf(m, 0.f);   // reference clamps max_patch at 0
    }
    __syncthreads();
  }
  if (tid == 0) out[0] = logf(total / (float)TT);
}

extern "C" void kernel_launch(void* const* d_in, const int* in_sizes, int n_in,
                              void* d_out, int out_size, void* d_ws, size_t ws_size,
                              hipStream_t stream) {
  const float* x  = (const float*)d_in[0];
  const float* xr = (const float*)d_in[1];
  float* patch = (float*)d_ws;      // 8192 floats = 32 KB scratch
  float* out   = (float*)d_out;

  patch_sum_kernel<<<NPATCH, 256, 0, stream>>>(x, xr, patch);
  finalize_kernel<<<1, 256, 0, stream>>>(patch, out);
}

// Round 2
// 215.430 us; speedup vs baseline: 1.0798x; 1.0798x over previous
//
#include <hip/hip_runtime.h>
#include <math.h>

// x, x_r: (1, 3, 32, 512, 512) fp32. size=64 -> hc=wc=32, nh=nw=16.
// P[t,ph,pw] = mean over (c=3, 32x32) of |x - x_r|/2   (3072 elems/patch)
// out = log( mean_t( max(0, max_{ph,pw} P) ) )  -- scalar fp32.
//
// Kernel 1: block per (ch,t,ph) stripe = 32 rows x 512 cols, contiguous 64KB.
//   Wave loads are 64 x float4 = 1KiB contiguous per instruction.
//   For f4 index f = i*256 + tid: col = (4*f)%512 = 4*(tid%128) -> the pw bin
//   (col/32 = (tid%128)/8) is CONSTANT per thread -> scalar accumulator.
// Kernel 2: one 1024-thread block sums 3 channel partials, per-t max, clamp,
//   mean, log. Fully parallel (no 32-iteration serial loop).

#define NPART 8192           // 32 t * 16 ph * 16 pw

__global__ __launch_bounds__(256) void patch_sum_kernel(
    const float* __restrict__ x, const float* __restrict__ xr,
    float* __restrict__ part) {
  const int b  = blockIdx.x;          // 0..1535 = ch*512 + t*16 + ph
  const int tid = threadIdx.x;
  // stripe base (floats): ((ch*32 + t)*512 + ph*32) * 512
  const size_t base = ((size_t)(b >> 4) * 512 + (size_t)(b & 15) * 32) * 512;
  const float4* __restrict__ a4 = (const float4*)(x  + base);
  const float4* __restrict__ b4 = (const float4*)(xr + base);

  float acc = 0.f;
#pragma unroll 8
  for (int i = 0; i < 16; ++i) {
    float4 a = a4[i * 256 + tid];
    float4 c = b4[i * 256 + tid];
    acc += fabsf(a.x - c.x) + fabsf(a.y - c.y)
         + fabsf(a.z - c.z) + fabsf(a.w - c.w);
  }

  // 16 pw bins; this thread's bin = (tid%128)/8. Reduce 8-lane groups first.
  __shared__ float s[16];
  if (tid < 16) s[tid] = 0.f;
  __syncthreads();
  acc += __shfl_down(acc, 4, 8);
  acc += __shfl_down(acc, 2, 8);
  acc += __shfl_down(acc, 1, 8);
  if ((tid & 7) == 0) atomicAdd(&s[(tid & 127) >> 3], acc);
  __syncthreads();
  // part index = b*16 + pw  ==  ch*8192 + t*256 + ph*16 + pw
  if (tid < 16) part[(size_t)b * 16 + tid] = s[tid];
}

__global__ __launch_bounds__(1024) void finalize_kernel(
    const float* __restrict__ part, float* __restrict__ out) {
  const int tid = threadIdx.x;
  const int t = tid >> 5;             // 0..31
  const int j = tid & 31;
  float m = -1e30f;
#pragma unroll
  for (int k = 0; k < 8; ++k) {
    int p = t * 256 + j + 32 * k;
    float v = part[p] + part[NPART + p] + part[2 * NPART + p];
    m = fmaxf(m, v);
  }
  // max over the 32 lanes covering this t (width-32 shuffle halves)
#pragma unroll
  for (int o = 16; o > 0; o >>= 1) m = fmaxf(m, __shfl_down(m, o, 32));
  __shared__ float s[32];
  if (j == 0) s[t] = fmaxf(m * (0.5f / 3072.0f), 0.f);  // scale + clamp at 0
  __syncthreads();
  if (tid < 32) {
    float v = s[tid];
#pragma unroll
    for (int o = 16; o > 0; o >>= 1) v += __shfl_down(v, o, 32);
    if (tid == 0) out[0] = logf(v * (1.0f / 32.0f));
  }
}

extern "C" void kernel_launch(void* const* d_in, const int* in_sizes, int n_in,
                              void* d_out, int out_size, void* d_ws, size_t ws_size,
                              hipStream_t stream) {
  const float* x  = (const float*)d_in[0];
  const float* xr = (const float*)d_in[1];
  float* part = (float*)d_ws;        // 3*8192 floats = 96 KB scratch
  float* out  = (float*)d_out;

  patch_sum_kernel<<<1536, 256, 0, stream>>>(x, xr, part);
  finalize_kernel<<<1, 1024, 0, stream>>>(part, out);
}

// Round 3
// 209.770 us; speedup vs baseline: 1.1089x; 1.0270x over previous
//
#include <hip/hip_runtime.h>
#include <math.h>

// x, x_r: (1, 3, 32, 512, 512) fp32. size=64 -> hc=wc=32, nh=nw=16.
// P[t,ph,pw] = mean over (c=3, 32x32) of |x - x_r|/2   (3072 elems/patch)
// out = log( mean_t( max(0, max_{ph,pw} P) ) )  -- scalar fp32.
//
// Kernel 1: 3072 blocks; block = (ch, t, ph, half): 32 rows x 256 cols of one
//   (ch,t) frame. Per-thread: 8 float4 loads per input, ALL issued before any
//   arithmetic (explicit arrays -> ~16 loads in flight -> max MLP per wave).
//   Wave-instruction footprint: 64 lanes x 16 B = 1 KiB contiguous row chunk.
//   f4 index idx = i*256+tid -> col4 = idx&63 -> pw bin = half*8 + (tid&63)>>3
//   is CONSTANT per thread -> scalar accumulator.
// Kernel 2: one 1024-thread block: sum 3 channel partials, per-t max, clamp,
//   mean, log (same as round 2 -- measured fast).

#define NPART 8192           // 32 t * 16 ph * 16 pw

__global__ __launch_bounds__(256) void patch_sum_kernel(
    const float* __restrict__ x, const float* __restrict__ xr,
    float* __restrict__ part) {
  const int b   = blockIdx.x;        // 0..3071 = ch*1024 + t*32 + ph*2 + half
  const int tid = threadIdx.x;
  const int ch   = b >> 10;
  const int rem  = b & 1023;
  const int t    = rem >> 5;
  const int sub  = rem & 31;         // ph*2 + half
  const int ph   = sub >> 1;
  const int half = sub & 1;
  // base in float4 units: ((ch*32+t)*512 + ph*32)*128 + half*64
  const size_t base4 = ((size_t)(ch * 32 + t) * 512 + (size_t)ph * 32) * 128
                     + (size_t)half * 64;
  const float4* __restrict__ a4 = (const float4*)x  + base4;
  const float4* __restrict__ b4 = (const float4*)xr + base4;

  // idx = i*256 + tid ; row = idx>>6 (0..31), col4 = idx&63 ; row stride 128 f4
  float4 a[8], c[8];
#pragma unroll
  for (int i = 0; i < 8; ++i) {
    int idx = i * 256 + tid;
    a[i] = a4[(size_t)(idx >> 6) * 128 + (idx & 63)];
  }
#pragma unroll
  for (int i = 0; i < 8; ++i) {
    int idx = i * 256 + tid;
    c[i] = b4[(size_t)(idx >> 6) * 128 + (idx & 63)];
  }

  float s0 = 0.f, s1 = 0.f, s2 = 0.f, s3 = 0.f;
#pragma unroll
  for (int i = 0; i < 8; ++i) {
    s0 += fabsf(a[i].x - c[i].x);
    s1 += fabsf(a[i].y - c[i].y);
    s2 += fabsf(a[i].z - c[i].z);
    s3 += fabsf(a[i].w - c[i].w);
  }
  float acc = (s0 + s1) + (s2 + s3);

  // 8 bins per block; thread's bin g = (tid&63)>>3. Reduce 8 consecutive lanes,
  // then 4 leaders per bin combine via LDS (no atomics).
  acc += __shfl_down(acc, 4, 8);
  acc += __shfl_down(acc, 2, 8);
  acc += __shfl_down(acc, 1, 8);
  __shared__ float s[32];            // [w][g] : w = leader wave-quarter 0..3
  if ((tid & 7) == 0) {
    int m = tid >> 3;                // 0..31
    s[(m >> 3) * 8 + (m & 7)] = acc;
  }
  __syncthreads();
  if (tid < 8) {
    float v = (s[tid] + s[8 + tid]) + (s[16 + tid] + s[24 + tid]);
    // part index = ch*8192 + t*256 + ph*16 + (half*8 + g)
    part[(size_t)ch * 8192 + t * 256 + ph * 16 + half * 8 + tid] = v;
  }
}

__global__ __launch_bounds__(1024) void finalize_kernel(
    const float* __restrict__ part, float* __restrict__ out) {
  const int tid = threadIdx.x;
  const int t = tid >> 5;             // 0..31
  const int j = tid & 31;
  float m = -1e30f;
#pragma unroll
  for (int k = 0; k < 8; ++k) {
    int p = t * 256 + j + 32 * k;
    float v = part[p] + part[NPART + p] + part[2 * NPART + p];
    m = fmaxf(m, v);
  }
#pragma unroll
  for (int o = 16; o > 0; o >>= 1) m = fmaxf(m, __shfl_down(m, o, 32));
  __shared__ float s[32];
  if (j == 0) s[t] = fmaxf(m * (0.5f / 3072.0f), 0.f);  // scale + clamp at 0
  __syncthreads();
  if (tid < 32) {
    float v = s[tid];
#pragma unroll
    for (int o = 16; o > 0; o >>= 1) v += __shfl_down(v, o, 32);
    if (tid == 0) out[0] = logf(v * (1.0f / 32.0f));
  }
}

extern "C" void kernel_launch(void* const* d_in, const int* in_sizes, int n_in,
                              void* d_out, int out_size, void* d_ws, size_t ws_size,
                              hipStream_t stream) {
  const float* x  = (const float*)d_in[0];
  const float* xr = (const float*)d_in[1];
  float* part = (float*)d_ws;        // 3*8192 floats = 96 KB scratch
  float* out  = (float*)d_out;

  patch_sum_kernel<<<3072, 256, 0, stream>>>(x, xr, part);
  finalize_kernel<<<1, 1024, 0, stream>>>(part, out);
}